// Round 5
// baseline (36169.272 us; speedup 1.0000x reference)
//
#include <hip/hip_runtime.h>

#define HIDDEN   2048
#define T_STEPS  8192
#define WASHOUT  200
#define NWG      128
#define NTHR     512
#define NWAVE    (NTHR / 64)                 // 8 waves
#define ROWS_PER_WG   (HIDDEN / NWG)         // 16
#define ROWS_PER_WAVE (ROWS_PER_WG / NWAVE)  // 2
#define MB       8                           // float4 col-blocks per lane

// ws layout: unsigned long long pairs[2][HIDDEN] -- {value:hi32, step:lo32}.
// One 8B atomic carries payload+tag: no fences, no flags, one round trip.
// 0xAA poison -> tag 0xAAAAAAAA never matches a real step: self-initializing.

// Weights live in AGPRs via explicit v_accvgpr_write/read: asm-defined values
// cannot be rematerialized from w_res, so per-step weight traffic is zero.
#define AG_W(dst, src) \
  asm volatile("v_accvgpr_write_b32 %0, %1" : "=a"(dst) : "v"(src))
#define AG_R(dst, src) \
  asm("v_accvgpr_read_b32 %0, %1" : "=v"(dst) : "a"(src))

__global__ __launch_bounds__(NTHR, 1) void esn_main(
    const float* __restrict__ u,
    const float* __restrict__ w_in,
    const float* __restrict__ w_res,
    const float* __restrict__ w_out,
    float* __restrict__ out,
    unsigned long long* __restrict__ pairs)
{
  const int g  = blockIdx.x;    // 0..127, one WG per CU
  const int j  = threadIdx.x;   // 0..511
  const int wv = j >> 6;        // 0..7
  const int l  = j & 63;

  __shared__ float x_s[2][HIDDEN];   // double-buffered staged state (16 KB)
  __shared__ float u_s[T_STEPS];     // 32 KB
  __shared__ float red[NWAVE];

#pragma unroll
  for (int k = 0; k < T_STEPS / NTHR; ++k) u_s[j + NTHR * k] = u[j + NTHR * k];

  // wave wv owns rows r0, r0+1; lane l owns cols {mb*256 + 4l .. +3}
  const int r0 = g * ROWS_PER_WG + wv * ROWS_PER_WAVE;

  float wa0[4 * MB], wa1[4 * MB];   // AGPR-resident weights (64 floats)
#pragma unroll
  for (int mb = 0; mb < MB; ++mb) {
    const float4 a = *(const float4*)&w_res[(r0 + 0) * HIDDEN + mb * 256 + 4 * l];
    const float4 b = *(const float4*)&w_res[(r0 + 1) * HIDDEN + mb * 256 + 4 * l];
    AG_W(wa0[4 * mb + 0], a.x); AG_W(wa0[4 * mb + 1], a.y);
    AG_W(wa0[4 * mb + 2], a.z); AG_W(wa0[4 * mb + 3], a.w);
    AG_W(wa1[4 * mb + 0], b.x); AG_W(wa1[4 * mb + 1], b.y);
    AG_W(wa1[4 * mb + 2], b.z); AG_W(wa1[4 * mb + 3], b.w);
  }

  const float win0 = w_in[r0];
  const float win1 = w_in[r0 + 1];
  const float4 wo  = *(const float4*)&w_out[4 * j];

  __syncthreads();  // u_s ready

  for (int t = 0; t < T_STEPS; ++t) {
    float d0 = 0.f, d1 = 0.f;
    if (t > 0) {
      const unsigned sp   = (unsigned)((t - 1) & 1);
      const unsigned want = (unsigned)(t - 1);
      const unsigned long long* bp = pairs + sp * HIDDEN + 4 * j;
      // parallel poll: 4 independent loads in flight, one RT per retry
      unsigned long long p0, p1, p2, p3;
      for (;;) {
        p0 = __hip_atomic_load(bp + 0, __ATOMIC_RELAXED, __HIP_MEMORY_SCOPE_AGENT);
        p1 = __hip_atomic_load(bp + 1, __ATOMIC_RELAXED, __HIP_MEMORY_SCOPE_AGENT);
        p2 = __hip_atomic_load(bp + 2, __ATOMIC_RELAXED, __HIP_MEMORY_SCOPE_AGENT);
        p3 = __hip_atomic_load(bp + 3, __ATOMIC_RELAXED, __HIP_MEMORY_SCOPE_AGENT);
        if ((((unsigned)p0 == want) & ((unsigned)p1 == want)) &
            (((unsigned)p2 == want) & ((unsigned)p3 == want))) break;
      }
      float4 xv;
      xv.x = __uint_as_float((unsigned)(p0 >> 32));
      xv.y = __uint_as_float((unsigned)(p1 >> 32));
      xv.z = __uint_as_float((unsigned)(p2 >> 32));
      xv.w = __uint_as_float((unsigned)(p3 >> 32));
      ((float4*)x_s[sp])[j] = xv;
      __syncthreads();  // staging complete (single barrier per step)

      const float4* xs4 = (const float4*)x_s[sp];
#pragma unroll
      for (int mb = 0; mb < MB; ++mb) {
        const float4 x4 = xs4[mb * 64 + l];   // ds_read_b128
        float w;
        AG_R(w, wa0[4 * mb + 0]); d0 = fmaf(w, x4.x, d0);
        AG_R(w, wa0[4 * mb + 1]); d0 = fmaf(w, x4.y, d0);
        AG_R(w, wa0[4 * mb + 2]); d0 = fmaf(w, x4.z, d0);
        AG_R(w, wa0[4 * mb + 3]); d0 = fmaf(w, x4.w, d0);
        AG_R(w, wa1[4 * mb + 0]); d1 = fmaf(w, x4.x, d1);
        AG_R(w, wa1[4 * mb + 1]); d1 = fmaf(w, x4.y, d1);
        AG_R(w, wa1[4 * mb + 2]); d1 = fmaf(w, x4.z, d1);
        AG_R(w, wa1[4 * mb + 3]); d1 = fmaf(w, x4.w, d1);
      }
    }
#pragma unroll
    for (int off = 32; off >= 1; off >>= 1) {
      d0 += __shfl_xor(d0, off, 64);
      d1 += __shfl_xor(d1, off, 64);
    }
    const float ut = u_s[t];
    if (l < ROWS_PER_WAVE) {
      const float dsel = (l == 0) ? d0 : d1;
      const float wsel = (l == 0) ? win0 : win1;
      const float xn = tanhf(fmaf(wsel, ut, dsel));
      const unsigned long long pk =
          ((unsigned long long)__float_as_uint(xn) << 32) | (unsigned)t;
      __hip_atomic_store(pairs + (t & 1) * HIDDEN + r0 + l, pk,
                         __ATOMIC_RELAXED, __HIP_MEMORY_SCOPE_AGENT);
    }

    // readout of x[t-1] (staged in x_s[(t-1)&1]), rotating WG, off critical path
    if (t >= WASHOUT + 1 && g == (t & (NWG - 1))) {
      const float4 xv = ((const float4*)x_s[(t - 1) & 1])[j];
      float p = fmaf(xv.x, wo.x, fmaf(xv.y, wo.y, fmaf(xv.z, wo.z, xv.w * wo.w)));
#pragma unroll
      for (int off = 32; off >= 1; off >>= 1) p += __shfl_xor(p, off, 64);
      if (l == 0) red[wv] = p;
      __syncthreads();
      if (j == 0) {
        float s = 0.f;
#pragma unroll
        for (int i = 0; i < NWAVE; ++i) s += red[i];
        out[t - 1 - WASHOUT] = s;
      }
    }
  }

  // epilogue: out[T-1-WASHOUT] = x[T-1] . w_out  (WG 0)
  if (g == 0) {
    const unsigned sp   = (unsigned)((T_STEPS - 1) & 1);
    const unsigned want = (unsigned)(T_STEPS - 1);
    const unsigned long long* bp = pairs + sp * HIDDEN + 4 * j;
    unsigned long long p0, p1, p2, p3;
    for (;;) {
      p0 = __hip_atomic_load(bp + 0, __ATOMIC_RELAXED, __HIP_MEMORY_SCOPE_AGENT);
      p1 = __hip_atomic_load(bp + 1, __ATOMIC_RELAXED, __HIP_MEMORY_SCOPE_AGENT);
      p2 = __hip_atomic_load(bp + 2, __ATOMIC_RELAXED, __HIP_MEMORY_SCOPE_AGENT);
      p3 = __hip_atomic_load(bp + 3, __ATOMIC_RELAXED, __HIP_MEMORY_SCOPE_AGENT);
      if ((((unsigned)p0 == want) & ((unsigned)p1 == want)) &
          (((unsigned)p2 == want) & ((unsigned)p3 == want))) break;
    }
    float4 xv;
    xv.x = __uint_as_float((unsigned)(p0 >> 32));
    xv.y = __uint_as_float((unsigned)(p1 >> 32));
    xv.z = __uint_as_float((unsigned)(p2 >> 32));
    xv.w = __uint_as_float((unsigned)(p3 >> 32));
    ((float4*)x_s[sp])[j] = xv;
    __syncthreads();
    const float4 x4 = ((const float4*)x_s[sp])[j];
    float p = fmaf(x4.x, wo.x, fmaf(x4.y, wo.y, fmaf(x4.z, wo.z, x4.w * wo.w)));
#pragma unroll
    for (int off = 32; off >= 1; off >>= 1) p += __shfl_xor(p, off, 64);
    if (l == 0) red[wv] = p;
    __syncthreads();
    if (j == 0) {
      float s = 0.f;
#pragma unroll
      for (int i = 0; i < NWAVE; ++i) s += red[i];
      out[T_STEPS - 1 - WASHOUT] = s;
    }
  }
}

extern "C" void kernel_launch(void* const* d_in, const int* in_sizes, int n_in,
                              void* d_out, int out_size, void* d_ws, size_t ws_size,
                              hipStream_t stream) {
  const float* u     = (const float*)d_in[0];
  const float* w_in  = (const float*)d_in[1];
  const float* w_res = (const float*)d_in[2];
  const float* w_out = (const float*)d_in[3];
  float* out = (float*)d_out;
  unsigned long long* pairs = (unsigned long long*)d_ws;

  esn_main<<<NWG, NTHR, 0, stream>>>(u, w_in, w_res, w_out, out, pairs);
}

// Round 6
// 25812.708 us; speedup vs baseline: 1.4012x; 1.4012x over previous
//
#include <hip/hip_runtime.h>

#define HIDDEN   2048
#define T_STEPS  8192
#define WASHOUT  200
#define NWG      128
#define NTHR     512
#define NWAVE    (NTHR / 64)                 // 8 waves
#define ROWS_PER_WG   (HIDDEN / NWG)         // 16
#define ROWS_PER_WAVE (ROWS_PER_WG / NWAVE)  // 2
#define MB       8                           // float4 col-blocks per lane

// ws layout: unsigned long long pairs[2][HIDDEN] -- {value:hi32, step:lo32}.
// One 8B atomic carries payload+tag: no fences, no flags, one round trip.
// 0xAA poison -> tag 0xAAAAAAAA never matches a real step: self-initializing.

// Weights live in AGPRs (asm-defined: cannot be rematerialized or refetched).
#define AG_W(dst, src) \
  asm volatile("v_accvgpr_write_b32 %0, %1" : "=a"(dst) : "v"(src))
#define AG_R(dst, src) \
  asm("v_accvgpr_read_b32 %0, %1" : "=v"(dst) : "a"(src))

__global__ __launch_bounds__(NTHR, 1) void esn_main(
    const float* __restrict__ u,
    const float* __restrict__ w_in,
    const float* __restrict__ w_res,
    const float* __restrict__ w_out,
    float* __restrict__ out,
    unsigned long long* __restrict__ pairs)
{
  const int g  = blockIdx.x;    // 0..127, one WG per CU
  const int j  = threadIdx.x;   // 0..511
  const int wv = j >> 6;        // 0..7
  const int l  = j & 63;

  __shared__ float x_s[2][HIDDEN];   // double-buffered staged state (16 KB)
  __shared__ float u_s[T_STEPS];     // 32 KB
  __shared__ float red[2][NWAVE];    // per-wave readout partials, by parity

#pragma unroll
  for (int k = 0; k < T_STEPS / NTHR; ++k) u_s[j + NTHR * k] = u[j + NTHR * k];

  // wave wv owns rows r0, r0+1; lane l owns cols {mb*256 + 4l .. +3}
  const int r0 = g * ROWS_PER_WG + wv * ROWS_PER_WAVE;

  float wa0[4 * MB], wa1[4 * MB];   // AGPR-resident weights (64 floats)
#pragma unroll
  for (int mb = 0; mb < MB; ++mb) {
    const float4 a = *(const float4*)&w_res[(r0 + 0) * HIDDEN + mb * 256 + 4 * l];
    const float4 b = *(const float4*)&w_res[(r0 + 1) * HIDDEN + mb * 256 + 4 * l];
    AG_W(wa0[4 * mb + 0], a.x); AG_W(wa0[4 * mb + 1], a.y);
    AG_W(wa0[4 * mb + 2], a.z); AG_W(wa0[4 * mb + 3], a.w);
    AG_W(wa1[4 * mb + 0], b.x); AG_W(wa1[4 * mb + 1], b.y);
    AG_W(wa1[4 * mb + 2], b.z); AG_W(wa1[4 * mb + 3], b.w);
  }

  const float win0 = w_in[r0];
  const float win1 = w_in[r0 + 1];
  const float wo0  = w_out[r0];
  const float wo1  = w_out[r0 + 1];

  __syncthreads();  // u_s ready

  for (int t = 0; t < T_STEPS; ++t) {
    float d0 = 0.f, d1 = 0.f;
    const unsigned sp = (unsigned)((t - 1) & 1);
    if (t > 0) {
      const unsigned want = (unsigned)(t - 1);
      // lane-contiguous: each wave instruction covers 512 B contiguous
      // (8 cache lines, no line-request amplification)
      const unsigned long long* bp = pairs + sp * HIDDEN + (wv << 8) + l;
      unsigned long long p0, p1, p2, p3;
      for (;;) {
        p0 = __hip_atomic_load(bp +   0, __ATOMIC_RELAXED, __HIP_MEMORY_SCOPE_AGENT);
        p1 = __hip_atomic_load(bp +  64, __ATOMIC_RELAXED, __HIP_MEMORY_SCOPE_AGENT);
        p2 = __hip_atomic_load(bp + 128, __ATOMIC_RELAXED, __HIP_MEMORY_SCOPE_AGENT);
        p3 = __hip_atomic_load(bp + 192, __ATOMIC_RELAXED, __HIP_MEMORY_SCOPE_AGENT);
        if ((((unsigned)p0 == want) & ((unsigned)p1 == want)) &
            (((unsigned)p2 == want) & ((unsigned)p3 == want))) break;
      }
      const int sb = (wv << 8) + l;
      x_s[sp][sb +   0] = __uint_as_float((unsigned)(p0 >> 32));
      x_s[sp][sb +  64] = __uint_as_float((unsigned)(p1 >> 32));
      x_s[sp][sb + 128] = __uint_as_float((unsigned)(p2 >> 32));
      x_s[sp][sb + 192] = __uint_as_float((unsigned)(p3 >> 32));
    }
    __syncthreads();  // staging complete (single barrier per step)

    if (t > 0) {
      const float4* xs4 = (const float4*)x_s[sp];
#pragma unroll
      for (int mb = 0; mb < MB; ++mb) {
        const float4 x4 = xs4[mb * 64 + l];   // ds_read_b128
        float w;
        AG_R(w, wa0[4 * mb + 0]); d0 = fmaf(w, x4.x, d0);
        AG_R(w, wa0[4 * mb + 1]); d0 = fmaf(w, x4.y, d0);
        AG_R(w, wa0[4 * mb + 2]); d0 = fmaf(w, x4.z, d0);
        AG_R(w, wa0[4 * mb + 3]); d0 = fmaf(w, x4.w, d0);
        AG_R(w, wa1[4 * mb + 0]); d1 = fmaf(w, x4.x, d1);
        AG_R(w, wa1[4 * mb + 1]); d1 = fmaf(w, x4.y, d1);
        AG_R(w, wa1[4 * mb + 2]); d1 = fmaf(w, x4.z, d1);
        AG_R(w, wa1[4 * mb + 3]); d1 = fmaf(w, x4.w, d1);
      }
    }
#pragma unroll
    for (int off = 32; off >= 1; off >>= 1) {
      d0 += __shfl_xor(d0, off, 64);
      d1 += __shfl_xor(d1, off, 64);
    }
    const float ut = u_s[t];
    float xn = 0.f;
    if (l < ROWS_PER_WAVE) {
      const float dsel = (l == 0) ? d0 : d1;
      const float wsel = (l == 0) ? win0 : win1;
      xn = tanhf(fmaf(wsel, ut, dsel));
      const unsigned long long pk =
          ((unsigned long long)__float_as_uint(xn) << 32) | (unsigned)t;
      // publish immediately: payload+tag in one atomic
      __hip_atomic_store(pairs + (t & 1) * HIDDEN + r0 + l, pk,
                         __ATOMIC_RELAXED, __HIP_MEMORY_SCOPE_AGENT);
    }

    // distributed readout: this WG's 2-row partial of x_t . w_out (lanes 0,1)
    float part = xn * ((l == 0) ? wo0 : wo1);
    part += __shfl_down(part, 1, 64);          // lane0 = row0 + row1
    if (l == 0) red[t & 1][wv] = part;

    // flush step t-1's partial (written last iter, visible via this iter's
    // barrier) -- one atomicAdd per WG, fire-and-forget, off critical path
    if (t >= WASHOUT + 1 && j == 0) {
      const float* rp = red[sp];
      float s = ((rp[0] + rp[1]) + (rp[2] + rp[3])) +
                ((rp[4] + rp[5]) + (rp[6] + rp[7]));
      atomicAdd(&out[t - 1 - WASHOUT], s);
    }
  }

  // epilogue: flush the final step's partial
  __syncthreads();
  if (j == 0) {
    const float* rp = red[(T_STEPS - 1) & 1];
    float s = ((rp[0] + rp[1]) + (rp[2] + rp[3])) +
              ((rp[4] + rp[5]) + (rp[6] + rp[7]));
    atomicAdd(&out[T_STEPS - 1 - WASHOUT], s);
  }
}

extern "C" void kernel_launch(void* const* d_in, const int* in_sizes, int n_in,
                              void* d_out, int out_size, void* d_ws, size_t ws_size,
                              hipStream_t stream) {
  const float* u     = (const float*)d_in[0];
  const float* w_in  = (const float*)d_in[1];
  const float* w_res = (const float*)d_in[2];
  const float* w_out = (const float*)d_in[3];
  float* out = (float*)d_out;
  unsigned long long* pairs = (unsigned long long*)d_ws;

  // out accumulates atomicAdd partials -> must start at zero every call
  hipMemsetAsync(out, 0, (size_t)out_size * sizeof(float), stream);
  esn_main<<<NWG, NTHR, 0, stream>>>(u, w_in, w_res, w_out, out, pairs);
}

// Round 7
// 21397.476 us; speedup vs baseline: 1.6904x; 1.2063x over previous
//
#include <hip/hip_runtime.h>

#define HIDDEN   2048
#define T_STEPS  8192
#define WASHOUT  200
#define NWG      64
#define NTHR     512
#define NWAVE    (NTHR / 64)                 // 8 waves
#define ROWS_PER_WG   (HIDDEN / NWG)         // 32
#define ROWS_PER_WAVE (ROWS_PER_WG / NWAVE)  // 4
#define MB       8                           // float4 col-blocks per lane

// ws layout: unsigned long long pairs[2][HIDDEN] -- {value:hi32, step:lo32}.
// One 8B atomic carries payload+tag: no fences, no flags, one round trip.
// 0xAA poison -> tag 0xAAAAAAAA never matches a real step: self-initializing.

// Weights live in AGPRs (asm-defined: cannot be rematerialized or refetched).
#define AG_W(dst, src) \
  asm volatile("v_accvgpr_write_b32 %0, %1" : "=a"(dst) : "v"(src))
#define AG_R(dst, src) \
  asm("v_accvgpr_read_b32 %0, %1" : "=v"(dst) : "a"(src))

__global__ __launch_bounds__(NTHR, 1) void esn_main(
    const float* __restrict__ u,
    const float* __restrict__ w_in,
    const float* __restrict__ w_res,
    const float* __restrict__ w_out,
    float* __restrict__ out,
    unsigned long long* __restrict__ pairs)
{
  const int g  = blockIdx.x;    // 0..63, one WG per CU
  const int j  = threadIdx.x;   // 0..511
  const int wv = j >> 6;        // 0..7
  const int l  = j & 63;

  __shared__ float x_s[2][HIDDEN];   // double-buffered staged state (16 KB)
  __shared__ float u_s[T_STEPS];     // 32 KB
  __shared__ float red[2][NWAVE];    // per-wave readout partials, by parity

#pragma unroll
  for (int k = 0; k < T_STEPS / NTHR; ++k) u_s[j + NTHR * k] = u[j + NTHR * k];

  // wave wv owns rows r0..r0+3; lane l owns cols {mb*256 + 4l .. +3}
  const int r0 = g * ROWS_PER_WG + wv * ROWS_PER_WAVE;

  float wa[ROWS_PER_WAVE][4 * MB];   // 128 AGPR-resident weights per thread
#pragma unroll
  for (int i = 0; i < ROWS_PER_WAVE; ++i) {
#pragma unroll
    for (int mb = 0; mb < MB; ++mb) {
      const float4 a = *(const float4*)&w_res[(r0 + i) * HIDDEN + mb * 256 + 4 * l];
      AG_W(wa[i][4 * mb + 0], a.x); AG_W(wa[i][4 * mb + 1], a.y);
      AG_W(wa[i][4 * mb + 2], a.z); AG_W(wa[i][4 * mb + 3], a.w);
    }
  }

  const float winl = w_in[r0 + (l & 3)];   // valid for lanes 0..3
  const float wol  = w_out[r0 + (l & 3)];

  __syncthreads();  // u_s ready

  for (int t = 0; t < T_STEPS; ++t) {
    float d0 = 0.f, d1 = 0.f, d2 = 0.f, d3 = 0.f;
    const unsigned sp = (unsigned)((t - 1) & 1);
    if (t > 0) {
      const unsigned want = (unsigned)(t - 1);
      // lane-contiguous: each wave instruction covers 512 B contiguous
      const unsigned long long* bp = pairs + sp * HIDDEN + (wv << 8) + l;
      unsigned long long p0, p1, p2, p3;
      for (;;) {
        p0 = __hip_atomic_load(bp +   0, __ATOMIC_RELAXED, __HIP_MEMORY_SCOPE_AGENT);
        p1 = __hip_atomic_load(bp +  64, __ATOMIC_RELAXED, __HIP_MEMORY_SCOPE_AGENT);
        p2 = __hip_atomic_load(bp + 128, __ATOMIC_RELAXED, __HIP_MEMORY_SCOPE_AGENT);
        p3 = __hip_atomic_load(bp + 192, __ATOMIC_RELAXED, __HIP_MEMORY_SCOPE_AGENT);
        if ((((unsigned)p0 == want) & ((unsigned)p1 == want)) &
            (((unsigned)p2 == want) & ((unsigned)p3 == want))) break;
      }
      const int sb = (wv << 8) + l;
      x_s[sp][sb +   0] = __uint_as_float((unsigned)(p0 >> 32));
      x_s[sp][sb +  64] = __uint_as_float((unsigned)(p1 >> 32));
      x_s[sp][sb + 128] = __uint_as_float((unsigned)(p2 >> 32));
      x_s[sp][sb + 192] = __uint_as_float((unsigned)(p3 >> 32));
    }
    __syncthreads();  // staging complete (single barrier per step)

    if (t > 0) {
      const float4* xs4 = (const float4*)x_s[sp];
#pragma unroll
      for (int mb = 0; mb < MB; ++mb) {
        const float4 x4 = xs4[mb * 64 + l];   // ds_read_b128
        float w;
        AG_R(w, wa[0][4 * mb + 0]); d0 = fmaf(w, x4.x, d0);
        AG_R(w, wa[0][4 * mb + 1]); d0 = fmaf(w, x4.y, d0);
        AG_R(w, wa[0][4 * mb + 2]); d0 = fmaf(w, x4.z, d0);
        AG_R(w, wa[0][4 * mb + 3]); d0 = fmaf(w, x4.w, d0);
        AG_R(w, wa[1][4 * mb + 0]); d1 = fmaf(w, x4.x, d1);
        AG_R(w, wa[1][4 * mb + 1]); d1 = fmaf(w, x4.y, d1);
        AG_R(w, wa[1][4 * mb + 2]); d1 = fmaf(w, x4.z, d1);
        AG_R(w, wa[1][4 * mb + 3]); d1 = fmaf(w, x4.w, d1);
        AG_R(w, wa[2][4 * mb + 0]); d2 = fmaf(w, x4.x, d2);
        AG_R(w, wa[2][4 * mb + 1]); d2 = fmaf(w, x4.y, d2);
        AG_R(w, wa[2][4 * mb + 2]); d2 = fmaf(w, x4.z, d2);
        AG_R(w, wa[2][4 * mb + 3]); d2 = fmaf(w, x4.w, d2);
        AG_R(w, wa[3][4 * mb + 0]); d3 = fmaf(w, x4.x, d3);
        AG_R(w, wa[3][4 * mb + 1]); d3 = fmaf(w, x4.y, d3);
        AG_R(w, wa[3][4 * mb + 2]); d3 = fmaf(w, x4.z, d3);
        AG_R(w, wa[3][4 * mb + 3]); d3 = fmaf(w, x4.w, d3);
      }
    }
#pragma unroll
    for (int off = 32; off >= 1; off >>= 1) {
      d0 += __shfl_xor(d0, off, 64);
      d1 += __shfl_xor(d1, off, 64);
      d2 += __shfl_xor(d2, off, 64);
      d3 += __shfl_xor(d3, off, 64);
    }
    const float ut = u_s[t];
    float xn = 0.f;
    if (l < ROWS_PER_WAVE) {
      const float dsel = (l == 0) ? d0 : (l == 1) ? d1 : (l == 2) ? d2 : d3;
      xn = tanhf(fmaf(winl, ut, dsel));
      const unsigned long long pk =
          ((unsigned long long)__float_as_uint(xn) << 32) | (unsigned)t;
      // publish immediately: payload+tag in one atomic
      __hip_atomic_store(pairs + (t & 1) * HIDDEN + r0 + l, pk,
                         __ATOMIC_RELAXED, __HIP_MEMORY_SCOPE_AGENT);
    }

    // distributed readout: this WG's 4-row partial of x_t . w_out (lanes 0..3)
    float part = xn * wol;                     // xn==0 for lanes >= 4
    part += __shfl_down(part, 2, 64);
    part += __shfl_down(part, 1, 64);          // lane0 = rows r0..r0+3
    if (l == 0) red[t & 1][wv] = part;

    // flush step t-1's partial (written last iter, visible via this iter's
    // barrier) -- one atomicAdd per WG, fire-and-forget, off critical path
    if (t >= WASHOUT + 1 && j == 0) {
      const float* rp = red[sp];
      float s = ((rp[0] + rp[1]) + (rp[2] + rp[3])) +
                ((rp[4] + rp[5]) + (rp[6] + rp[7]));
      atomicAdd(&out[t - 1 - WASHOUT], s);
    }
  }

  // epilogue: flush the final step's partial
  __syncthreads();
  if (j == 0) {
    const float* rp = red[(T_STEPS - 1) & 1];
    float s = ((rp[0] + rp[1]) + (rp[2] + rp[3])) +
              ((rp[4] + rp[5]) + (rp[6] + rp[7]));
    atomicAdd(&out[T_STEPS - 1 - WASHOUT], s);
  }
}

extern "C" void kernel_launch(void* const* d_in, const int* in_sizes, int n_in,
                              void* d_out, int out_size, void* d_ws, size_t ws_size,
                              hipStream_t stream) {
  const float* u     = (const float*)d_in[0];
  const float* w_in  = (const float*)d_in[1];
  const float* w_res = (const float*)d_in[2];
  const float* w_out = (const float*)d_in[3];
  float* out = (float*)d_out;
  unsigned long long* pairs = (unsigned long long*)d_ws;

  // out accumulates atomicAdd partials -> must start at zero every call
  hipMemsetAsync(out, 0, (size_t)out_size * sizeof(float), stream);
  esn_main<<<NWG, NTHR, 0, stream>>>(u, w_in, w_res, w_out, out, pairs);
}